// Round 14
// baseline (391.974 us; speedup 1.0000x reference)
//
#include <hip/hip_runtime.h>
#include <stdint.h>

#define TOK   4096
#define DIM   1024
#define NH    16
#define DHD   64
#define NE    8
#define HIDN  2048
#define BATCH 2
#define SEQ   2048
#define BK    64

using floatx4 = __attribute__((ext_vector_type(4))) float;
using bfx8    = __attribute__((ext_vector_type(8))) __bf16;
using bfx2    = __attribute__((ext_vector_type(2))) __bf16;
using shortx8 = __attribute__((ext_vector_type(8))) short;

__device__ __forceinline__ unsigned short f2bf(float f) {
    union { __bf16 b; unsigned short u; } v;
    v.b = (__bf16)f;
    return v.u;
}

__device__ __forceinline__ float bf2f(unsigned short u) {
    union { unsigned u; float f; } v;
    v.u = (unsigned)u << 16;
    return v.f;
}

__device__ __forceinline__ unsigned pack2bf(float lo, float hi) {
    union { bfx2 v; unsigned u; } t;
    t.v[0] = (__bf16)lo;
    t.v[1] = (__bf16)hi;
    return t.u;
}

// fast tanh-form GELU
__device__ __forceinline__ float fast_gelu(float v) {
    float vc = v * (1.0f + 0.044715f * v * v);
    float e  = __builtin_amdgcn_exp2f(fminf(vc * 2.302264f, 80.0f));
    return v * e * __builtin_amdgcn_rcpf(e + 1.0f);
}

__device__ __forceinline__ floatx4 mfma16(bfx8 a, bfx8 b, floatx4 c) {
    return __builtin_amdgcn_mfma_f32_16x16x32_bf16(a, b, c, 0, 0, 0);
}

__device__ __forceinline__ void gload16(const unsigned short* g, unsigned short* l) {
    __builtin_amdgcn_global_load_lds(
        (const __attribute__((address_space(1))) unsigned int*)g,
        (__attribute__((address_space(3))) unsigned int*)l, 16, 0, 0);
}

// bijective XCD-aware remap (m204)
__device__ __forceinline__ int xcd_swz(int hw, int nwg) {
    int q = nwg >> 3, r = nwg & 7;
    int xc = hw & 7, o = hw >> 3;
    return (xc < r ? xc * (q + 1) : r * (q + 1) + (xc - r) * q) + o;
}

// ---------------- f32 -> bf16 straight convert ----------------
__global__ __launch_bounds__(256) void cvt_kernel(const float* __restrict__ in,
                                                  unsigned short* __restrict__ out, int n) {
    int i = (blockIdx.x * 256 + threadIdx.x) * 4;
    if (i < n) {
        float4 v = *reinterpret_cast<const float4*>(in + i);
        out[i + 0] = f2bf(v.x);
        out[i + 1] = f2bf(v.y);
        out[i + 2] = f2bf(v.z);
        out[i + 3] = f2bf(v.w);
    }
}

// ---------------- f32 [R][C] -> bf16 [C][R] transpose-convert (per expert z) ----------------
__global__ __launch_bounds__(256) void transpose_cvt_kernel(const float* __restrict__ in,
                                                            unsigned short* __restrict__ out,
                                                            int R, int C) {
    __shared__ unsigned short t[64][65];
    in  += (size_t)blockIdx.z * R * C;
    out += (size_t)blockIdx.z * R * C;
    int r0 = blockIdx.y * 64, c0 = blockIdx.x * 64;
    int lr = threadIdx.x >> 4, lc = (threadIdx.x & 15) * 4;
#pragma unroll
    for (int p = 0; p < 4; p++) {
        int r = p * 16 + lr;
        float4 v = *reinterpret_cast<const float4*>(in + (size_t)(r0 + r) * C + c0 + lc);
        t[lc + 0][r] = f2bf(v.x);
        t[lc + 1][r] = f2bf(v.y);
        t[lc + 2][r] = f2bf(v.z);
        t[lc + 3][r] = f2bf(v.w);
    }
    __syncthreads();
    int c = threadIdx.x >> 2, ch = (threadIdx.x & 3) * 16;
    shortx8 o0, o1;
#pragma unroll
    for (int q = 0; q < 8; q++) { o0[q] = t[c][ch + q]; o1[q] = t[c][ch + 8 + q]; }
    unsigned short* op = out + (size_t)(c0 + c) * R + r0 + ch;
    *reinterpret_cast<shortx8*>(op) = o0;
    *reinterpret_cast<shortx8*>(op + 8) = o1;
}

// ---- K,V of qkv -> ktg[b,h][s][d] + vtg[b,h][d][s]; also mask -> float (log2 domain) ----
__global__ __launch_bounds__(256) void kvprep_kernel(const unsigned short* __restrict__ qkv,
                                                     unsigned short* __restrict__ ktg,
                                                     unsigned short* __restrict__ vtg,
                                                     const unsigned char* __restrict__ mask,
                                                     float* __restrict__ maskf) {
    __shared__ unsigned short t[64 * 64];
    int tid = threadIdx.x;
    int s0 = blockIdx.x * 64, hd = blockIdx.y, b = blockIdx.z;
    size_t bh = (size_t)(b * NH + hd);
    if (hd == 0 && tid < 64) {
        maskf[(size_t)b * SEQ + s0 + tid] =
            mask[(size_t)b * SEQ + s0 + tid] ? -1.44269504e9f : 0.0f;
    }
#pragma unroll
    for (int i = 0; i < 2; i++) {
        int idx = i * 256 + tid;
        int sr = idx >> 3, c = idx & 7;
        shortx8 v = *reinterpret_cast<const shortx8*>(
            qkv + (size_t)(b * SEQ + s0 + sr) * 3 * DIM + DIM + hd * DHD + c * 8);
        *reinterpret_cast<shortx8*>(ktg + (bh * SEQ + s0 + sr) * DHD + c * 8) = v;
    }
#pragma unroll
    for (int i = 0; i < 2; i++) {
        int idx = i * 256 + tid;
        int sr = idx >> 3, c = idx & 7;
        shortx8 v = *reinterpret_cast<const shortx8*>(
            qkv + (size_t)(b * SEQ + s0 + sr) * 3 * DIM + 2 * DIM + hd * DHD + c * 8);
        *reinterpret_cast<shortx8*>(t + sr * 64 + ((c ^ (sr >> 3)) * 8)) = v;
    }
    __syncthreads();
#pragma unroll
    for (int i = 0; i < 2; i++) {
        int idx = i * 256 + tid;
        int d = idx >> 3, c2 = idx & 7;
        shortx8 o;
#pragma unroll
        for (int e = 0; e < 8; e++) {
            int s = c2 * 8 + e;
            o[e] = (short)t[s * 64 + (((d >> 3) ^ c2) * 8) + (d & 7)];
        }
        *reinterpret_cast<shortx8*>(vtg + (bh * DHD + d) * SEQ + s0 + c2 * 8) = o;
    }
}

// ---------------- layernorm: one block per row ----------------
__global__ __launch_bounds__(256) void ln_kernel(const float* __restrict__ x,
                                                 const float* __restrict__ g,
                                                 const float* __restrict__ b,
                                                 unsigned short* __restrict__ obf) {
    int t = blockIdx.x;
    int tid = threadIdx.x;
    const float* xr = x + (size_t)t * DIM;
    float4 v = *reinterpret_cast<const float4*>(xr + tid * 4);
    float s  = v.x + v.y + v.z + v.w;
    float s2 = v.x * v.x + v.y * v.y + v.z * v.z + v.w * v.w;
    for (int o = 32; o > 0; o >>= 1) {
        s  += __shfl_down(s,  o, 64);
        s2 += __shfl_down(s2, o, 64);
    }
    __shared__ float red[10];
    int lane = tid & 63, w = tid >> 6;
    if (lane == 0) { red[w] = s; red[4 + w] = s2; }
    __syncthreads();
    if (tid == 0) {
        float ts = red[0] + red[1] + red[2] + red[3];
        float t2 = red[4] + red[5] + red[6] + red[7];
        float mu = ts * (1.0f / DIM);
        float var = t2 * (1.0f / DIM) - mu * mu;
        red[8] = mu;
        red[9] = rsqrtf(var + 1e-5f);
    }
    __syncthreads();
    float mu = red[8], rstd = red[9];
    float4 gv = *reinterpret_cast<const float4*>(g + tid * 4);
    float4 bv = *reinterpret_cast<const float4*>(b + tid * 4);
    size_t o = (size_t)t * DIM + tid * 4;
    obf[o + 0] = f2bf((v.x - mu) * rstd * gv.x + bv.x);
    obf[o + 1] = f2bf((v.y - mu) * rstd * gv.y + bv.y);
    obf[o + 2] = f2bf((v.z - mu) * rstd * gv.z + bv.z);
    obf[o + 3] = f2bf((v.w - mu) * rstd * gv.w + bv.w);
}

// ---------------- MFMA GEMM 128x128 (m97 structure + XCD swizzle) ----------------
template <int EPI, bool GATHER>
__global__ __launch_bounds__(256) void gemm_kernel(const unsigned short* __restrict__ A,
                                                   const unsigned short* __restrict__ Bt,
                                                   void* __restrict__ C,
                                                   const float* __restrict__ bias,
                                                   const float* __restrict__ resid,
                                                   const int* __restrict__ cnt,
                                                   const int* __restrict__ goff,
                                                   const int* __restrict__ gtok,
                                                   int M, int N, int K) {
    int gx = gridDim.x, gy = gridDim.y;
    int nwg = gx * gy * (int)gridDim.z;
    int hw = ((int)blockIdx.z * gy + (int)blockIdx.y) * gx + (int)blockIdx.x;
    int virt = xcd_swz(hw, nwg);
    int bx = virt % gx;
    int tmp = virt / gx;
    int by = tmp % gy;
    int e = tmp / gy;

    int Me = cnt ? cnt[e] : M;
    int brow = by * 128;
    if (brow >= Me) return;
    int bcol = bx * 128;
    int go = goff ? goff[e] : 0;
    const unsigned short* Be = Bt + (size_t)e * N * K;
    const float* biasp = bias + (size_t)e * N;

    __shared__ unsigned short As[128 * BK];
    __shared__ unsigned short Bs[128 * BK];

    int tid = threadIdx.x, lane = tid & 63, w = tid >> 6;
    int wr = w >> 1, wc = w & 1;
    int cg = lane >> 4, cl = lane & 15;

    const unsigned short* aga[4];
    const unsigned short* bga[4];
    unsigned short* asb = As + w * 2048;
    unsigned short* bsb = Bs + w * 2048;
#pragma unroll
    for (int i = 0; i < 4; i++) {
        int s = w * 256 + i * 64 + lane;
        int row = s >> 3;
        int c = (s & 7) ^ (row & 7);
        int gr = brow + row;
        if (gr >= Me) gr = Me - 1;
        long ar;
        if (GATHER) ar = gtok[go + gr];
        else if (cnt) ar = go + gr;
        else ar = gr;
        aga[i] = A + ar * (long)K + c * 8;
        bga[i] = Be + (size_t)(bcol + row) * K + c * 8;
    }

    floatx4 acc[4][4];
#pragma unroll
    for (int m = 0; m < 4; m++)
#pragma unroll
        for (int n = 0; n < 4; n++) acc[m][n] = (floatx4){0.f, 0.f, 0.f, 0.f};

    for (int kt = 0; kt < K; kt += BK) {
#pragma unroll
        for (int i = 0; i < 4; i++) {
            gload16(aga[i], asb + i * 512);
            gload16(bga[i], bsb + i * 512);
            aga[i] += BK;
            bga[i] += BK;
        }
        __syncthreads();
#pragma unroll
        for (int ks = 0; ks < 2; ks++) {
            bfx8 af[4], bf[4];
#pragma unroll
            for (int m = 0; m < 4; m++) {
                int row = wr * 64 + m * 16 + cl;
                af[m] = *reinterpret_cast<const bfx8*>(
                    As + row * BK + (((ks * 4 + cg) ^ (row & 7)) << 3));
            }
#pragma unroll
            for (int n = 0; n < 4; n++) {
                int row = wc * 64 + n * 16 + cl;
                bf[n] = *reinterpret_cast<const bfx8*>(
                    Bs + row * BK + (((ks * 4 + cg) ^ (row & 7)) << 3));
            }
#pragma unroll
            for (int m = 0; m < 4; m++)
#pragma unroll
                for (int n = 0; n < 4; n++) acc[m][n] = mfma16(af[m], bf[n], acc[m][n]);
        }
        __syncthreads();
    }

#pragma unroll
    for (int m = 0; m < 4; m++) {
#pragma unroll
        for (int j = 0; j < 4; j++) {
            int r = brow + wr * 64 + m * 16 + cg * 4 + j;
            if (r >= Me) continue;
#pragma unroll
            for (int n = 0; n < 4; n++) {
                int col = bcol + wc * 64 + n * 16 + cl;
                float v = acc[m][n][j] + biasp[col];
                if (EPI == 0) {
                    ((unsigned short*)C)[(size_t)r * N + col] = f2bf(v);
                } else if (EPI == 1) {
                    size_t o = (size_t)r * N + col;
                    ((float*)C)[o] = v + resid[o];
                } else if (EPI == 2) {
                    ((unsigned short*)C)[(size_t)(go + r) * N + col] = f2bf(fast_gelu(v));
                } else {
                    ((unsigned short*)C)[(size_t)(go + r) * N + col] = f2bf(v);
                }
            }
        }
    }
}

// ---------------- MFMA GEMM 256xBN, 8 waves, 2-phase dbuf (m248v2 geometry) ----------------
// Sync structure identical to the round-9 correctness-proven dbuf loop:
// prologue stage + one barrier; loop { prefetch nb; ds_read cur; MFMA; barrier }.
// BN=256: LDS 128 KB; BN=128: 96 KB. 1 block/CU, 8 waves (2M x 4N).
template <int EPI, bool GATHER, int BN>
__global__ __launch_bounds__(512, 2) void gemm256_kernel(const unsigned short* __restrict__ A,
                                                         const unsigned short* __restrict__ Bt,
                                                         void* __restrict__ C,
                                                         const float* __restrict__ bias,
                                                         const int* __restrict__ cnt,
                                                         const int* __restrict__ goff,
                                                         const int* __restrict__ gtok,
                                                         int M, int N, int K) {
    constexpr int NREP = BN / 64;     // 4 (BN=256) or 2 (BN=128)
    constexpr int RB   = BN / 64;     // B staging rounds
    int gx = gridDim.x, gy = gridDim.y;
    int nwg = gx * gy * (int)gridDim.z;
    int hw = ((int)blockIdx.z * gy + (int)blockIdx.y) * gx + (int)blockIdx.x;
    int virt = xcd_swz(hw, nwg);
    int bx = virt % gx;
    int tmp = virt / gx;
    int by = tmp % gy;
    int e = tmp / gy;

    int Me = cnt[e];
    int brow = by * 256;
    if (brow >= Me) return;
    int bcol = bx * BN;
    int go = goff[e];
    const unsigned short* Be = Bt + (size_t)e * N * K;
    const float* biasp = bias + (size_t)e * N;

    __shared__ unsigned short As[2][256 * BK];
    __shared__ unsigned short Bs[2][BN * BK];

    int tid = threadIdx.x, lane = tid & 63, w = tid >> 6;
    int wr = w >> 2, wc = w & 3;      // 2M x 4N
    int cg = lane >> 4, cl = lane & 15;

    // staging: A 4 rounds, B RB rounds; slot s = r*512 + tid; row=s>>3, chunk=s&7
    const unsigned short* aga[4];
    const unsigned short* bga[RB];
#pragma unroll
    for (int r = 0; r < 4; r++) {
        int s = r * 512 + tid;
        int row = s >> 3;
        int c = (s & 7) ^ (row & 7);
        int gr = brow + row;
        if (gr >= Me) gr = Me - 1;
        long ar;
        if (GATHER) ar = gtok[go + gr];
        else ar = go + gr;
        aga[r] = A + ar * (long)K + c * 8;
    }
#pragma unroll
    for (int r = 0; r < RB; r++) {
        int s = r * 512 + tid;
        int row = s >> 3;
        int c = (s & 7) ^ (row & 7);
        bga[r] = Be + (size_t)(bcol + row) * K + c * 8;
    }

    floatx4 acc[8][NREP];
#pragma unroll
    for (int m = 0; m < 8; m++)
#pragma unroll
        for (int n = 0; n < NREP; n++) acc[m][n] = (floatx4){0.f, 0.f, 0.f, 0.f};

    // prologue: stage K-tile 0 into buffer 0
#pragma unroll
    for (int r = 0; r < 4; r++) { gload16(aga[r], &As[0][(r * 512 + tid) * 8]); aga[r] += BK; }
#pragma unroll
    for (int r = 0; r < RB; r++) { gload16(bga[r], &Bs[0][(r * 512 + tid) * 8]); bga[r] += BK; }
    __syncthreads();

    int nt = K / BK;
    int cur = 0;
    for (int t = 0; t < nt; t++) {
        if (t + 1 < nt) {
            int nb = cur ^ 1;
#pragma unroll
            for (int r = 0; r < 4; r++) { gload16(aga[r], &As[nb][(r * 512 + tid) * 8]); aga[r] += BK; }
#pragma unroll
            for (int r = 0; r < RB; r++) { gload16(bga[r], &Bs[nb][(r * 512 + tid) * 8]); bga[r] += BK; }
        }
        const unsigned short* asb = &As[cur][0];
        const unsigned short* bsb = &Bs[cur][0];
#pragma unroll
        for (int ks = 0; ks < 2; ks++) {
            bfx8 af[8], bf[NREP];
#pragma unroll
            for (int m = 0; m < 8; m++) {
                int row = wr * 128 + m * 16 + cl;
                af[m] = *reinterpret_cast<const bfx8*>(
                    asb + row * BK + (((ks * 4 + cg) ^ (row & 7)) << 3));
            }
#pragma unroll
            for (int n = 0; n < NREP; n++) {
                int row = wc * (BN / 4) + n * 16 + cl;
                bf[n] = *reinterpret_cast<const bfx8*>(
                    bsb + row * BK + (((ks * 4 + cg) ^ (row & 7)) << 3));
            }
            __builtin_amdgcn_s_setprio(1);
#pragma unroll
            for (int m = 0; m < 8; m++)
#pragma unroll
                for (int n = 0; n < NREP; n++) acc[m][n] = mfma16(af[m], bf[n], acc[m][n]);
            __builtin_amdgcn_s_setprio(0);
        }
        __syncthreads();
        cur ^= 1;
    }

#pragma unroll
    for (int m = 0; m < 8; m++) {
#pragma unroll
        for (int j = 0; j < 4; j++) {
            int r = brow + wr * 128 + m * 16 + cg * 4 + j;
            if (r >= Me) continue;
#pragma unroll
            for (int n = 0; n < NREP; n++) {
                int col = bcol + wc * (BN / 4) + n * 16 + cl;
                float v = acc[m][n][j] + biasp[col];
                if (EPI == 2) {
                    ((unsigned short*)C)[(size_t)(go + r) * N + col] = f2bf(fast_gelu(v));
                } else {
                    ((unsigned short*)C)[(size_t)(go + r) * N + col] = f2bf(v);
                }
            }
        }
    }
}

// ---------------- flash attention: 128 q/block, 8 waves, dbuf K/V, XCD-swizzled grid ----------------
__global__ __launch_bounds__(512, 2) void attn_kernel(const unsigned short* __restrict__ qkv,
                                                      const unsigned short* __restrict__ ktg,
                                                      const unsigned short* __restrict__ vtg,
                                                      const float* __restrict__ maskf,
                                                      unsigned short* __restrict__ ao) {
    __shared__ unsigned short Ks[2][64 * 64];
    __shared__ unsigned short Vs[2][64 * 64];
    __shared__ unsigned short Ps[8][16 * 72];

    int tid = threadIdx.x, lane = tid & 63, w = tid >> 6;
    int cg = lane >> 4, cl = lane & 15;
    // XCD swizzle: all 16 q-blocks of one (b,hd) land in one XCD chunk (K/V L2 reuse)
    int gx = gridDim.x, gy = gridDim.y;
    int nwg = gx * gy * (int)gridDim.z;
    int hw = ((int)blockIdx.z * gy + (int)blockIdx.y) * gx + (int)blockIdx.x;
    int virt = xcd_swz(hw, nwg);
    int qx = virt % gx;
    int tmp = virt / gx;
    int hd = tmp % gy;
    int b = tmp / gy;
    int qb = qx * 128;
    size_t bh = (size_t)(b * NH + hd);
    const float SC2 = 0.125f * 1.44269504f;

    int tq = qb + w * 16 + cl;
    const unsigned short* qrow = qkv + (size_t)(b * SEQ + tq) * 3 * DIM + hd * DHD;
    bfx8 aq0 = *reinterpret_cast<const bfx8*>(qrow + cg * 8);
    bfx8 aq1 = *reinterpret_cast<const bfx8*>(qrow + 32 + cg * 8);

    int srow8 = lane >> 3, schunk = lane & 7;
    int csrc = schunk ^ srow8;
    const unsigned short* kptr = ktg + (bh * SEQ + w * 8 + srow8) * DHD + csrc * 8;
    const unsigned short* vptr = vtg + (bh * DHD + w * 8 + srow8) * SEQ + csrc * 8;
    const float* mrowf = maskf + (size_t)b * SEQ;
    unsigned short* psw = &Ps[w][0];
    int sw0 = (cg ^ (cl & 7)) << 3;

    floatx4 accO[4];
#pragma unroll
    for (int dt = 0; dt < 4; dt++) accO[dt] = (floatx4){0.f, 0.f, 0.f, 0.f};
    float m0 = -3.0e38f, l0 = 0.f;

    gload16(kptr, &Ks[0][tid * 8]);
    gload16(vptr, &Vs[0][tid * 8]);
    __syncthreads();

    int cur = 0;
    for (int t = 0; t < SEQ / 64; t++) {
        if (t < SEQ / 64 - 1) {
            size_t nkt = (size_t)(t + 1) * 64;
            int nb = cur ^ 1;
            gload16(kptr + nkt * DHD, &Ks[nb][tid * 8]);
            gload16(vptr + nkt, &Vs[nb][tid * 8]);
        }
        const unsigned short* ksb = &Ks[cur][0];
        const unsigned short* vsb = &Vs[cur][0];
        int kt = t * 64;

        float4 mk[4];
#pragma unroll
        for (int nt = 0; nt < 4; nt++)
            mk[nt] = *reinterpret_cast<const float4*>(mrowf + kt + nt * 16 + cg * 4);

        floatx4 accS[4];
#pragma unroll
        for (int nt = 0; nt < 4; nt++) accS[nt] = (floatx4){0.f, 0.f, 0.f, 0.f};
        __builtin_amdgcn_s_setprio(1);
#pragma unroll
        for (int nt = 0; nt < 4; nt++) {
            const unsigned short* kr = ksb + (nt * 16 + cl) * 64;
            bfx8 k0 = *reinterpret_cast<const bfx8*>(kr + sw0);
            bfx8 k1 = *reinterpret_cast<const bfx8*>(kr + (sw0 ^ 32));
            accS[nt] = mfma16(k0, aq0, accS[nt]);
            accS[nt] = mfma16(k1, aq1, accS[nt]);
        }
        __builtin_amdgcn_s_setprio(0);

        float s[4][4];
        float pm[4];
#pragma unroll
        for (int nt = 0; nt < 4; nt++) {
            s[nt][0] = fmaf(accS[nt][0], SC2, mk[nt].x);
            s[nt][1] = fmaf(accS[nt][1], SC2, mk[nt].y);
            s[nt][2] = fmaf(accS[nt][2], SC2, mk[nt].z);
            s[nt][3] = fmaf(accS[nt][3], SC2, mk[nt].w);
            pm[nt] = fmaxf(fmaxf(s[nt][0], s[nt][1]), fmaxf(s[nt][2], s[nt][3]));
        }
        float tmax = fmaxf(fmaxf(pm[0], pm[1]), fmaxf(pm[2], pm[3]));
        if (!__all(tmax - m0 <= 11.5f)) {
            tmax = fmaxf(tmax, __shfl_xor(tmax, 16, 64));
            tmax = fmaxf(tmax, __shfl_xor(tmax, 32, 64));
            float mn = fmaxf(m0, tmax);
            float al = __builtin_amdgcn_exp2f(m0 - mn);
            m0 = mn;
            l0 *= al;
#pragma unroll
            for (int dt = 0; dt < 4; dt++) accO[dt] *= al;
        }

        float rs = 0.f;
#pragma unroll
        for (int nt = 0; nt < 4; nt++) {
            float p0 = __builtin_amdgcn_exp2f(s[nt][0] - m0);
            float p1 = __builtin_amdgcn_exp2f(s[nt][1] - m0);
            float p2 = __builtin_amdgcn_exp2f(s[nt][2] - m0);
            float p3 = __builtin_amdgcn_exp2f(s[nt][3] - m0);
            rs += (p0 + p1) + (p2 + p3);
            uint2 u;
            u.x = pack2bf(p0, p1);
            u.y = pack2bf(p2, p3);
            *reinterpret_cast<uint2*>(psw + cl * 72 + nt * 16 + cg * 4) = u;
        }
        rs += __shfl_xor(rs, 16, 64);
        rs += __shfl_xor(rs, 32, 64);
        l0 += rs;

        bfx8 pf0 = *reinterpret_cast<const bfx8*>(psw + cl * 72 + cg * 8);
        bfx8 pf1 = *reinterpret_cast<const bfx8*>(psw + cl * 72 + 32 + cg * 8);
        __builtin_amdgcn_s_setprio(1);
#pragma unroll
        for (int dt = 0; dt < 4; dt++) {
            const unsigned short* vr = vsb + (dt * 16 + cl) * 64;
            bfx8 v0 = *reinterpret_cast<const bfx8*>(vr + sw0);
            bfx8 v1 = *reinterpret_cast<const bfx8*>(vr + (sw0 ^ 32));
            accO[dt] = mfma16(v0, pf0, accO[dt]);
            accO[dt] = mfma16(v1, pf1, accO[dt]);
        }
        __builtin_amdgcn_s_setprio(0);
        __syncthreads();
        cur ^= 1;
    }

    float rl = 1.0f / l0;
    unsigned short* aorow = ao + (size_t)(b * SEQ + qb + w * 16 + cl) * DIM + hd * DHD;
#pragma unroll
    for (int dt = 0; dt < 4; dt++) {
        uint2 u;
        u.x = pack2bf(accO[dt][0] * rl, accO[dt][1] * rl);
        u.y = pack2bf(accO[dt][2] * rl, accO[dt][3] * rl);
        *reinterpret_cast<uint2*>(aorow + dt * 16 + cg * 4) = u;
    }
}

// ---------------- fused LN2 + gating ----------------
__global__ __launch_bounds__(256) void gate_kernel(const float* __restrict__ x2,
                                                   const float* __restrict__ lng,
                                                   const float* __restrict__ lnb,
                                                   const float* __restrict__ Wg,
                                                   const float* __restrict__ bg,
                                                   unsigned short* __restrict__ xn2b,
                                                   int* __restrict__ idx,
                                                   float* __restrict__ wts,
                                                   float* __restrict__ me_part) {
    __shared__ float bme[8];
    if (threadIdx.x < 8) bme[threadIdx.x] = 0.f;
    __syncthreads();
    int w = threadIdx.x >> 6, lane = threadIdx.x & 63;
    int t = blockIdx.x * 4 + w;
    const float* xr = x2 + (size_t)t * DIM + lane * 16;
    float4 xv[4];
    float s = 0.f, s2 = 0.f;
#pragma unroll
    for (int q = 0; q < 4; q++) {
        xv[q] = *reinterpret_cast<const float4*>(xr + q * 4);
        s  += xv[q].x + xv[q].y + xv[q].z + xv[q].w;
        s2 += xv[q].x * xv[q].x + xv[q].y * xv[q].y + xv[q].z * xv[q].z + xv[q].w * xv[q].w;
    }
    for (int o = 32; o > 0; o >>= 1) {
        s  += __shfl_xor(s,  o, 64);
        s2 += __shfl_xor(s2, o, 64);
    }
    float mu = s * (1.0f / DIM);
    float rstd = rsqrtf(s2 * (1.0f / DIM) - mu * mu + 1e-5f);
    float acc[8];
#pragma unroll
    for (int e = 0; e < 8; e++) acc[e] = 0.f;
    unsigned short ob[16];
#pragma unroll
    for (int q = 0; q < 4; q++) {
        float4 gv = *reinterpret_cast<const float4*>(lng + lane * 16 + q * 4);
        float4 bv = *reinterpret_cast<const float4*>(lnb + lane * 16 + q * 4);
        float xn0 = (xv[q].x - mu) * rstd * gv.x + bv.x;
        float xn1 = (xv[q].y - mu) * rstd * gv.y + bv.y;
        float xn2 = (xv[q].z - mu) * rstd * gv.z + bv.z;
        float xn3 = (xv[q].w - mu) * rstd * gv.w + bv.w;
        ob[q * 4 + 0] = f2bf(xn0);
        ob[q * 4 + 1] = f2bf(xn1);
        ob[q * 4 + 2] = f2bf(xn2);
        ob[q * 4 + 3] = f2bf(xn3);
        const float* wr = Wg + (size_t)(lane * 16 + q * 4) * 8;
#pragma unroll
        for (int e = 0; e < 8; e++) acc[e] += xn0 * wr[e];
#pragma unroll
        for (int e = 0; e < 8; e++) acc[e] += xn1 * wr[8 + e];
#pragma unroll
        for (int e = 0; e < 8; e++) acc[e] += xn2 * wr[16 + e];
#pragma unroll
        for (int e = 0; e < 8; e++) acc[e] += xn3 * wr[24 + e];
    }
    unsigned short* op = xn2b + (size_t)t * DIM + lane * 16;
    *reinterpret_cast<shortx8*>(op)     = *reinterpret_cast<shortx8*>(&ob[0]);
    *reinterpret_cast<shortx8*>(op + 8) = *reinterpret_cast<shortx8*>(&ob[8]);
    for (int o = 32; o > 0; o >>= 1)
#pragma unroll
        for (int e = 0; e < 8; e++) acc[e] += __shfl_xor(acc[e], o, 64);
    if (lane == 0) {
        float p[8];
        float mx = -3e38f;
#pragma unroll
        for (int e = 0; e < 8; e++) { acc[e] += bg[e]; mx = fmaxf(mx, acc[e]); }
        float se = 0.f;
#pragma unroll
        for (int e = 0; e < 8; e++) { p[e] = expf(acc[e] - mx); se += p[e]; }
#pragma unroll
        for (int e = 0; e < 8; e++) p[e] /= se;
        int i0 = 0; float v0 = p[0];
#pragma unroll
        for (int e = 1; e < 8; e++) if (p[e] > v0) { v0 = p[e]; i0 = e; }
        int i1 = -1; float v1 = -3e38f;
#pragma unroll
        for (int e = 0; e < 8; e++) if (e != i0 && p[e] > v1) { v1 = p[e]; i1 = e; }
        float sw = v0 + v1;
        idx[t * 2]     = i0;
        idx[t * 2 + 1] = i1;
        wts[t * 2]     = v0 / sw;
        wts[t * 2 + 1] = v1 / sw;
#pragma unroll
        for (int e = 0; e < 8; e++) atomicAdd(&bme[e], p[e]);
    }
    __syncthreads();
    if (threadIdx.x < 8) me_part[(size_t)blockIdx.x * 8 + threadIdx.x] = bme[threadIdx.x];
}

// ---------------- routing pass 1 ----------------
__global__ __launch_bounds__(256) void route1_kernel(const int* __restrict__ idx,
                                                     int* __restrict__ cnt,
                                                     int* __restrict__ posl) {
    __shared__ int lh[8];
    __shared__ int gb[8];
    int tid = threadIdx.x;
    int t = blockIdx.x * 256 + tid;
    if (tid < 8) lh[tid] = 0;
    __syncthreads();
    int i0 = idx[t * 2], i1 = idx[t * 2 + 1];
    int r0 = atomicAdd(&lh[i0], 1);
    int r1 = atomicAdd(&lh[i1], 1);
    __syncthreads();
    if (tid < 8) gb[tid] = atomicAdd(&cnt[tid], lh[tid]);
    __syncthreads();
    posl[t * 2]     = gb[i0] + r0;
    posl[t * 2 + 1] = gb[i1] + r1;
}

__global__ void prefix_kernel(const int* __restrict__ cnt, int* __restrict__ goff) {
    if (threadIdx.x == 0) {
        int s = 0;
        for (int e = 0; e < 8; e++) { goff[e] = s; s += cnt[e]; }
        goff[8] = s;
    }
}

// ---------------- routing pass 2 ----------------
__global__ __launch_bounds__(256) void route2_kernel(const int* __restrict__ idx,
                                                     const int* __restrict__ goff,
                                                     const int* __restrict__ posl,
                                                     int* __restrict__ gtok,
                                                     int* __restrict__ tpos) {
    int t = blockIdx.x * 256 + threadIdx.x;
#pragma unroll
    for (int j = 0; j < 2; j++) {
        int e = idx[t * 2 + j];
        int p = goff[e] + posl[t * 2 + j];
        gtok[p] = t;
        tpos[t * 2 + j] = p;
    }
}

// ---------------- combine: eo is bf16 ----------------
__global__ __launch_bounds__(256) void combine_kernel(const float* __restrict__ x2,
                                                      const unsigned short* __restrict__ eo,
                                                      const float* __restrict__ wts,
                                                      const int* __restrict__ tpos,
                                                      float* __restrict__ out) {
    int t = blockIdx.x;
    int c = threadIdx.x * 4;
    float w0 = wts[t * 2], w1 = wts[t * 2 + 1];
    int p0 = tpos[t * 2], p1 = tpos[t * 2 + 1];
    float4 r = *reinterpret_cast<const float4*>(x2 + (size_t)t * DIM + c);
    ushort4 a4 = *reinterpret_cast<const ushort4*>(eo + (size_t)p0 * DIM + c);
    ushort4 b4 = *reinterpret_cast<const ushort4*>(eo + (size_t)p1 * DIM + c);
    float4 o;
    o.x = r.x + w0 * bf2f(a4.x) + w1 * bf2f(b4.x);
    o.y = r.y + w0 * bf2f(a4.y) + w1 * bf2f(b4.y);
    o.z = r.z + w0 * bf2f(a4.z) + w1 * bf2f(b4.z);
    o.w = r.w + w0 * bf2f(a4.w) + w1 * bf2f(b4.w);
    *reinterpret_cast<float4*>(out + (size_t)t * DIM + c) = o;
}

// ---------------- loss ----------------
__global__ __launch_bounds__(256) void loss_kernel(const float* __restrict__ me_part,
                                                   const int* __restrict__ cnt,
                                                   float* __restrict__ out) {
    __shared__ float red[256];
    int tid = threadIdx.x;
    int e = tid & 7, part = tid >> 3;
    float s = 0.f;
    for (int b = part; b < 1024; b += 32) s += me_part[(size_t)b * 8 + e];
    red[tid] = s;
    __syncthreads();
    if (tid < 64) {
        float v = red[tid] + red[tid + 64] + red[tid + 128] + red[tid + 192];
        red[tid] = v;
    }
    __syncthreads();
    if (tid < 8) {
        float v = red[tid] + red[tid + 8] + red[tid + 16] + red[tid + 24] +
                  red[tid + 32] + red[tid + 40] + red[tid + 48] + red[tid + 56];
        red[tid] = v;
    }
    __syncthreads();
    if (tid == 0) {
        float s2 = 0.f;
        for (int ee = 0; ee < 8; ee++)
            s2 += (red[ee] / 4096.0f) * ((float)cnt[ee] / 4096.0f);
        out[(size_t)TOK * DIM] = 8.0f * s2;
    }
}

extern "C" void kernel_launch(void* const* d_in, const int* in_sizes, int n_in,
                              void* d_out, int out_size, void* d_ws, size_t ws_size,
                              hipStream_t stream) {
    const float* x    = (const float*)d_in[0];
    const unsigned char* mask = (const unsigned char*)d_in[1];
    const float* ln1g = (const float*)d_in[2];
    const float* ln1b = (const float*)d_in[3];
    const float* Wqkv = (const float*)d_in[4];
    const float* bqkv = (const float*)d_in[5];
    const float* Wo   = (const float*)d_in[6];
    const float* bo   = (const float*)d_in[7];
    const float* ln2g = (const float*)d_in[8];
    const float* ln2b = (const float*)d_in[9];
    const float* Wg   = (const float*)d_in[10];
    const float* bg   = (const float*)d_in[11];
    const float* W1   = (const float*)d_in[12];
    const float* b1   = (const float*)d_in[13];
    const float* W2   = (const float*)d_in[14];
    const float* b2   = (const float*)d_in[15];
    float* out = (float*)d_out;

    char* ws = (char*)d_ws;
    int*   cnt  = (int*)(ws + 0);
    int*   goff = (int*)(ws + 128);
    size_t off = 1024;
    auto alloc = [&](size_t bytes) -> void* {
        void* p = ws + off;
        off += (bytes + 255) & ~(size_t)255;
        return p;
    };
    const size_t SZ_QKVB = (size_t)TOK * 3 * DIM * 2;
    const size_t SZ_HB   = (size_t)2 * TOK * HIDN * 2;
    char* R1 = (char*)alloc(SZ_HB > SZ_QKVB ? SZ_HB : SZ_QKVB);
    const size_t SZ_R2 = (size_t)2 * TOK * DIM * 2 + (size_t)3 * DIM * DIM * 2 +
                         (size_t)DIM * DIM * 2;
    char* R2 = (char*)alloc(SZ_R2);
    unsigned short* qkvb  = (unsigned short*)R1;
    unsigned short* hb    = (unsigned short*)R1;
    unsigned short* eo16  = (unsigned short*)R2;
    unsigned short* xn1   = (unsigned short*)R2;
    unsigned short* aob   = (unsigned short*)(R2 + (size_t)TOK * DIM * 2);
    unsigned short* wqkvb = (unsigned short*)(R2 + (size_t)2 * TOK * DIM * 2);
    unsigned short* wob   = (unsigned short*)(R2 + (size_t)2 * TOK * DIM * 2 +
                                              (size_t)3 * DIM * DIM * 2);
    float*          x2    = (float*)alloc((size_t)TOK * DIM * 4);
    unsigned short* xn2b  = (unsigned short*)alloc((size_t)TOK * DIM * 2);
    unsigned short* w1t   = (unsigned short*)alloc((size_t)NE * DIM * HIDN * 2);
    unsigned short* w2t   = (unsigned short*)alloc((size_t)NE * DIM * HIDN * 2);
    unsigned short* ktg   = (unsigned short*)alloc((size_t)BATCH * NH * SEQ * DHD * 2);
    unsigned short* vtg   = (unsigned short*)alloc((size_t)BATCH * NH * DHD * SEQ * 2);
    float*          maskf = (float*)alloc((size_t)BATCH * SEQ * 4);
    float*          mep   = (float*)alloc((size_t)1024 * 8 * 4);
    int*            idxp  = (int*)alloc((size_t)TOK * 2 * 4);
    float*          wtsp  = (float*)alloc((size_t)TOK * 2 * 4);
    int*            posl  = (int*)alloc((size_t)TOK * 2 * 4);
    int*            gtok  = (int*)alloc((size_t)2 * TOK * 4);
    int*            tpos  = (int*)alloc((size_t)TOK * 2 * 4);

    hipMemsetAsync(ws, 0, 256, stream);

    cvt_kernel<<<3 * DIM * DIM / 1024, 256, 0, stream>>>(Wqkv, wqkvb, 3 * DIM * DIM);
    cvt_kernel<<<DIM * DIM / 1024, 256, 0, stream>>>(Wo, wob, DIM * DIM);
    transpose_cvt_kernel<<<dim3(HIDN / 64, DIM / 64, NE), 256, 0, stream>>>(W1, w1t, DIM, HIDN);
    transpose_cvt_kernel<<<dim3(DIM / 64, HIDN / 64, NE), 256, 0, stream>>>(W2, w2t, HIDN, DIM);

    ln_kernel<<<TOK, 256, 0, stream>>>(x, ln1g, ln1b, xn1);

    gemm_kernel<0, false><<<dim3(24, 32, 1), 256, 0, stream>>>(
        xn1, wqkvb, qkvb, bqkv, nullptr, nullptr, nullptr, nullptr, TOK, 3 * DIM, DIM);

    kvprep_kernel<<<dim3(SEQ / 64, NH, BATCH), 256, 0, stream>>>(qkvb, ktg, vtg, mask, maskf);

    attn_kernel<<<dim3(SEQ / 128, NH, BATCH), 512, 0, stream>>>(qkvb, ktg, vtg, maskf, aob);

    gemm_kernel<1, false><<<dim3(8, 32, 1), 256, 0, stream>>>(
        aob, wob, x2, bo, x, nullptr, nullptr, nullptr, TOK, DIM, DIM);

    gate_kernel<<<TOK / 4, 256, 0, stream>>>(x2, ln2g, ln2b, Wg, bg, xn2b,
                                             idxp, wtsp, mep);
    route1_kernel<<<TOK / 256, 256, 0, stream>>>(idxp, cnt, posl);
    prefix_kernel<<<1, 64, 0, stream>>>(cnt, goff);
    route2_kernel<<<TOK / 256, 256, 0, stream>>>(idxp, goff, posl, gtok, tpos);

    gemm256_kernel<2, true, 256><<<dim3(HIDN / 256, 16, 8), 512, 0, stream>>>(
        xn2b, w1t, hb, b1, cnt, goff, gtok, TOK, HIDN, DIM);

    gemm256_kernel<3, false, 128><<<dim3(DIM / 128, 16, 8), 512, 0, stream>>>(
        hb, w2t, eo16, b2, cnt, goff, nullptr, TOK, DIM, HIDN);

    combine_kernel<<<TOK, 256, 0, stream>>>(x2, eo16, wtsp, tpos, out);
    loss_kernel<<<1, 256, 0, stream>>>(mep, cnt, out);
}

// Round 15
// 334.253 us; speedup vs baseline: 1.1727x; 1.1727x over previous
//
#include <hip/hip_runtime.h>
#include <stdint.h>

#define TOK   4096
#define DIM   1024
#define NH    16
#define DHD   64
#define NE    8
#define HIDN  2048
#define BATCH 2
#define SEQ   2048
#define BK    64

using floatx4 = __attribute__((ext_vector_type(4))) float;
using bfx8    = __attribute__((ext_vector_type(8))) __bf16;
using bfx2    = __attribute__((ext_vector_type(2))) __bf16;
using shortx8 = __attribute__((ext_vector_type(8))) short;

__device__ __forceinline__ unsigned short f2bf(float f) {
    union { __bf16 b; unsigned short u; } v;
    v.b = (__bf16)f;
    return v.u;
}

__device__ __forceinline__ float bf2f(unsigned short u) {
    union { unsigned u; float f; } v;
    v.u = (unsigned)u << 16;
    return v.f;
}

__device__ __forceinline__ unsigned pack2bf(float lo, float hi) {
    union { bfx2 v; unsigned u; } t;
    t.v[0] = (__bf16)lo;
    t.v[1] = (__bf16)hi;
    return t.u;
}

// fast tanh-form GELU
__device__ __forceinline__ float fast_gelu(float v) {
    float vc = v * (1.0f + 0.044715f * v * v);
    float e  = __builtin_amdgcn_exp2f(fminf(vc * 2.302264f, 80.0f));
    return v * e * __builtin_amdgcn_rcpf(e + 1.0f);
}

__device__ __forceinline__ floatx4 mfma16(bfx8 a, bfx8 b, floatx4 c) {
    return __builtin_amdgcn_mfma_f32_16x16x32_bf16(a, b, c, 0, 0, 0);
}

__device__ __forceinline__ void gload16(const unsigned short* g, unsigned short* l) {
    __builtin_amdgcn_global_load_lds(
        (const __attribute__((address_space(1))) unsigned int*)g,
        (__attribute__((address_space(3))) unsigned int*)l, 16, 0, 0);
}

// bijective XCD-aware remap (m204)
__device__ __forceinline__ int xcd_swz(int hw, int nwg) {
    int q = nwg >> 3, r = nwg & 7;
    int xc = hw & 7, o = hw >> 3;
    return (xc < r ? xc * (q + 1) : r * (q + 1) + (xc - r) * q) + o;
}

// ---------------- f32 -> bf16 straight convert ----------------
__global__ __launch_bounds__(256) void cvt_kernel(const float* __restrict__ in,
                                                  unsigned short* __restrict__ out, int n) {
    int i = (blockIdx.x * 256 + threadIdx.x) * 4;
    if (i < n) {
        float4 v = *reinterpret_cast<const float4*>(in + i);
        out[i + 0] = f2bf(v.x);
        out[i + 1] = f2bf(v.y);
        out[i + 2] = f2bf(v.z);
        out[i + 3] = f2bf(v.w);
    }
}

// ---------------- f32 [R][C] -> bf16 [C][R] transpose-convert (per expert z) ----------------
__global__ __launch_bounds__(256) void transpose_cvt_kernel(const float* __restrict__ in,
                                                            unsigned short* __restrict__ out,
                                                            int R, int C) {
    __shared__ unsigned short t[64][65];
    in  += (size_t)blockIdx.z * R * C;
    out += (size_t)blockIdx.z * R * C;
    int r0 = blockIdx.y * 64, c0 = blockIdx.x * 64;
    int lr = threadIdx.x >> 4, lc = (threadIdx.x & 15) * 4;
#pragma unroll
    for (int p = 0; p < 4; p++) {
        int r = p * 16 + lr;
        float4 v = *reinterpret_cast<const float4*>(in + (size_t)(r0 + r) * C + c0 + lc);
        t[lc + 0][r] = f2bf(v.x);
        t[lc + 1][r] = f2bf(v.y);
        t[lc + 2][r] = f2bf(v.z);
        t[lc + 3][r] = f2bf(v.w);
    }
    __syncthreads();
    int c = threadIdx.x >> 2, ch = (threadIdx.x & 3) * 16;
    shortx8 o0, o1;
#pragma unroll
    for (int q = 0; q < 8; q++) { o0[q] = t[c][ch + q]; o1[q] = t[c][ch + 8 + q]; }
    unsigned short* op = out + (size_t)(c0 + c) * R + r0 + ch;
    *reinterpret_cast<shortx8*>(op) = o0;
    *reinterpret_cast<shortx8*>(op + 8) = o1;
}

// ---- K,V of qkv -> ktg[b,h][s][d] + vtg[b,h][d][s]; also mask -> float (log2 domain) ----
__global__ __launch_bounds__(256) void kvprep_kernel(const unsigned short* __restrict__ qkv,
                                                     unsigned short* __restrict__ ktg,
                                                     unsigned short* __restrict__ vtg,
                                                     const unsigned char* __restrict__ mask,
                                                     float* __restrict__ maskf) {
    __shared__ unsigned short t[64 * 64];
    int tid = threadIdx.x;
    int s0 = blockIdx.x * 64, hd = blockIdx.y, b = blockIdx.z;
    size_t bh = (size_t)(b * NH + hd);
    if (hd == 0 && tid < 64) {
        maskf[(size_t)b * SEQ + s0 + tid] =
            mask[(size_t)b * SEQ + s0 + tid] ? -1.44269504e9f : 0.0f;
    }
#pragma unroll
    for (int i = 0; i < 2; i++) {
        int idx = i * 256 + tid;
        int sr = idx >> 3, c = idx & 7;
        shortx8 v = *reinterpret_cast<const shortx8*>(
            qkv + (size_t)(b * SEQ + s0 + sr) * 3 * DIM + DIM + hd * DHD + c * 8);
        *reinterpret_cast<shortx8*>(ktg + (bh * SEQ + s0 + sr) * DHD + c * 8) = v;
    }
#pragma unroll
    for (int i = 0; i < 2; i++) {
        int idx = i * 256 + tid;
        int sr = idx >> 3, c = idx & 7;
        shortx8 v = *reinterpret_cast<const shortx8*>(
            qkv + (size_t)(b * SEQ + s0 + sr) * 3 * DIM + 2 * DIM + hd * DHD + c * 8);
        *reinterpret_cast<shortx8*>(t + sr * 64 + ((c ^ (sr >> 3)) * 8)) = v;
    }
    __syncthreads();
#pragma unroll
    for (int i = 0; i < 2; i++) {
        int idx = i * 256 + tid;
        int d = idx >> 3, c2 = idx & 7;
        shortx8 o;
#pragma unroll
        for (int e = 0; e < 8; e++) {
            int s = c2 * 8 + e;
            o[e] = (short)t[s * 64 + (((d >> 3) ^ c2) * 8) + (d & 7)];
        }
        *reinterpret_cast<shortx8*>(vtg + (bh * DHD + d) * SEQ + s0 + c2 * 8) = o;
    }
}

// ---------------- layernorm: one block per row ----------------
__global__ __launch_bounds__(256) void ln_kernel(const float* __restrict__ x,
                                                 const float* __restrict__ g,
                                                 const float* __restrict__ b,
                                                 unsigned short* __restrict__ obf) {
    int t = blockIdx.x;
    int tid = threadIdx.x;
    const float* xr = x + (size_t)t * DIM;
    float4 v = *reinterpret_cast<const float4*>(xr + tid * 4);
    float s  = v.x + v.y + v.z + v.w;
    float s2 = v.x * v.x + v.y * v.y + v.z * v.z + v.w * v.w;
    for (int o = 32; o > 0; o >>= 1) {
        s  += __shfl_down(s,  o, 64);
        s2 += __shfl_down(s2, o, 64);
    }
    __shared__ float red[10];
    int lane = tid & 63, w = tid >> 6;
    if (lane == 0) { red[w] = s; red[4 + w] = s2; }
    __syncthreads();
    if (tid == 0) {
        float ts = red[0] + red[1] + red[2] + red[3];
        float t2 = red[4] + red[5] + red[6] + red[7];
        float mu = ts * (1.0f / DIM);
        float var = t2 * (1.0f / DIM) - mu * mu;
        red[8] = mu;
        red[9] = rsqrtf(var + 1e-5f);
    }
    __syncthreads();
    float mu = red[8], rstd = red[9];
    float4 gv = *reinterpret_cast<const float4*>(g + tid * 4);
    float4 bv = *reinterpret_cast<const float4*>(b + tid * 4);
    size_t o = (size_t)t * DIM + tid * 4;
    obf[o + 0] = f2bf((v.x - mu) * rstd * gv.x + bv.x);
    obf[o + 1] = f2bf((v.y - mu) * rstd * gv.y + bv.y);
    obf[o + 2] = f2bf((v.z - mu) * rstd * gv.z + bv.z);
    obf[o + 3] = f2bf((v.w - mu) * rstd * gv.w + bv.w);
}

// ---------------- MFMA GEMM 128x128 (m97 structure + XCD swizzle) ----------------
template <int EPI, bool GATHER>
__global__ __launch_bounds__(256) void gemm_kernel(const unsigned short* __restrict__ A,
                                                   const unsigned short* __restrict__ Bt,
                                                   void* __restrict__ C,
                                                   const float* __restrict__ bias,
                                                   const float* __restrict__ resid,
                                                   const int* __restrict__ cnt,
                                                   const int* __restrict__ goff,
                                                   const int* __restrict__ gtok,
                                                   int M, int N, int K) {
    int gx = gridDim.x, gy = gridDim.y;
    int nwg = gx * gy * (int)gridDim.z;
    int hw = ((int)blockIdx.z * gy + (int)blockIdx.y) * gx + (int)blockIdx.x;
    int virt = xcd_swz(hw, nwg);
    int bx = virt % gx;
    int tmp = virt / gx;
    int by = tmp % gy;
    int e = tmp / gy;

    int Me = cnt ? cnt[e] : M;
    int brow = by * 128;
    if (brow >= Me) return;
    int bcol = bx * 128;
    int go = goff ? goff[e] : 0;
    const unsigned short* Be = Bt + (size_t)e * N * K;
    const float* biasp = bias + (size_t)e * N;

    __shared__ unsigned short As[128 * BK];
    __shared__ unsigned short Bs[128 * BK];

    int tid = threadIdx.x, lane = tid & 63, w = tid >> 6;
    int wr = w >> 1, wc = w & 1;
    int cg = lane >> 4, cl = lane & 15;

    const unsigned short* aga[4];
    const unsigned short* bga[4];
    unsigned short* asb = As + w * 2048;
    unsigned short* bsb = Bs + w * 2048;
#pragma unroll
    for (int i = 0; i < 4; i++) {
        int s = w * 256 + i * 64 + lane;
        int row = s >> 3;
        int c = (s & 7) ^ (row & 7);
        int gr = brow + row;
        if (gr >= Me) gr = Me - 1;
        long ar;
        if (GATHER) ar = gtok[go + gr];
        else if (cnt) ar = go + gr;
        else ar = gr;
        aga[i] = A + ar * (long)K + c * 8;
        bga[i] = Be + (size_t)(bcol + row) * K + c * 8;
    }

    floatx4 acc[4][4];
#pragma unroll
    for (int m = 0; m < 4; m++)
#pragma unroll
        for (int n = 0; n < 4; n++) acc[m][n] = (floatx4){0.f, 0.f, 0.f, 0.f};

    for (int kt = 0; kt < K; kt += BK) {
#pragma unroll
        for (int i = 0; i < 4; i++) {
            gload16(aga[i], asb + i * 512);
            gload16(bga[i], bsb + i * 512);
            aga[i] += BK;
            bga[i] += BK;
        }
        __syncthreads();
#pragma unroll
        for (int ks = 0; ks < 2; ks++) {
            bfx8 af[4], bf[4];
#pragma unroll
            for (int m = 0; m < 4; m++) {
                int row = wr * 64 + m * 16 + cl;
                af[m] = *reinterpret_cast<const bfx8*>(
                    As + row * BK + (((ks * 4 + cg) ^ (row & 7)) << 3));
            }
#pragma unroll
            for (int n = 0; n < 4; n++) {
                int row = wc * 64 + n * 16 + cl;
                bf[n] = *reinterpret_cast<const bfx8*>(
                    Bs + row * BK + (((ks * 4 + cg) ^ (row & 7)) << 3));
            }
#pragma unroll
            for (int m = 0; m < 4; m++)
#pragma unroll
                for (int n = 0; n < 4; n++) acc[m][n] = mfma16(af[m], bf[n], acc[m][n]);
        }
        __syncthreads();
    }

#pragma unroll
    for (int m = 0; m < 4; m++) {
#pragma unroll
        for (int j = 0; j < 4; j++) {
            int r = brow + wr * 64 + m * 16 + cg * 4 + j;
            if (r >= Me) continue;
#pragma unroll
            for (int n = 0; n < 4; n++) {
                int col = bcol + wc * 64 + n * 16 + cl;
                float v = acc[m][n][j] + biasp[col];
                if (EPI == 0) {
                    ((unsigned short*)C)[(size_t)r * N + col] = f2bf(v);
                } else if (EPI == 1) {
                    size_t o = (size_t)r * N + col;
                    ((float*)C)[o] = v + resid[o];
                } else if (EPI == 2) {
                    ((unsigned short*)C)[(size_t)(go + r) * N + col] = f2bf(fast_gelu(v));
                } else {
                    ((unsigned short*)C)[(size_t)(go + r) * N + col] = f2bf(v);
                }
            }
        }
    }
}

// ---------------- flash attention: 128 q/block, 8 waves, dbuf K/V, XCD-swizzled grid ----------------
__global__ __launch_bounds__(512, 2) void attn_kernel(const unsigned short* __restrict__ qkv,
                                                      const unsigned short* __restrict__ ktg,
                                                      const unsigned short* __restrict__ vtg,
                                                      const float* __restrict__ maskf,
                                                      unsigned short* __restrict__ ao) {
    __shared__ unsigned short Ks[2][64 * 64];
    __shared__ unsigned short Vs[2][64 * 64];
    __shared__ unsigned short Ps[8][16 * 72];

    int tid = threadIdx.x, lane = tid & 63, w = tid >> 6;
    int cg = lane >> 4, cl = lane & 15;
    // XCD swizzle: the 16 q-blocks of one (b,hd) land in one XCD chunk (K/V L2 reuse)
    int gx = gridDim.x, gy = gridDim.y;
    int nwg = gx * gy * (int)gridDim.z;
    int hw = ((int)blockIdx.z * gy + (int)blockIdx.y) * gx + (int)blockIdx.x;
    int virt = xcd_swz(hw, nwg);
    int qx = virt % gx;
    int tmp = virt / gx;
    int hd = tmp % gy;
    int b = tmp / gy;
    int qb = qx * 128;
    size_t bh = (size_t)(b * NH + hd);
    const float SC2 = 0.125f * 1.44269504f;

    int tq = qb + w * 16 + cl;
    const unsigned short* qrow = qkv + (size_t)(b * SEQ + tq) * 3 * DIM + hd * DHD;
    bfx8 aq0 = *reinterpret_cast<const bfx8*>(qrow + cg * 8);
    bfx8 aq1 = *reinterpret_cast<const bfx8*>(qrow + 32 + cg * 8);

    int srow8 = lane >> 3, schunk = lane & 7;
    int csrc = schunk ^ srow8;
    const unsigned short* kptr = ktg + (bh * SEQ + w * 8 + srow8) * DHD + csrc * 8;
    const unsigned short* vptr = vtg + (bh * DHD + w * 8 + srow8) * SEQ + csrc * 8;
    const float* mrowf = maskf + (size_t)b * SEQ;
    unsigned short* psw = &Ps[w][0];
    int sw0 = (cg ^ (cl & 7)) << 3;

    floatx4 accO[4];
#pragma unroll
    for (int dt = 0; dt < 4; dt++) accO[dt] = (floatx4){0.f, 0.f, 0.f, 0.f};
    float m0 = -3.0e38f, l0 = 0.f;

    gload16(kptr, &Ks[0][tid * 8]);
    gload16(vptr, &Vs[0][tid * 8]);
    __syncthreads();

    int cur = 0;
    for (int t = 0; t < SEQ / 64; t++) {
        if (t < SEQ / 64 - 1) {
            size_t nkt = (size_t)(t + 1) * 64;
            int nb = cur ^ 1;
            gload16(kptr + nkt * DHD, &Ks[nb][tid * 8]);
            gload16(vptr + nkt, &Vs[nb][tid * 8]);
        }
        const unsigned short* ksb = &Ks[cur][0];
        const unsigned short* vsb = &Vs[cur][0];
        int kt = t * 64;

        float4 mk[4];
#pragma unroll
        for (int nt = 0; nt < 4; nt++)
            mk[nt] = *reinterpret_cast<const float4*>(mrowf + kt + nt * 16 + cg * 4);

        floatx4 accS[4];
#pragma unroll
        for (int nt = 0; nt < 4; nt++) accS[nt] = (floatx4){0.f, 0.f, 0.f, 0.f};
        __builtin_amdgcn_s_setprio(1);
#pragma unroll
        for (int nt = 0; nt < 4; nt++) {
            const unsigned short* kr = ksb + (nt * 16 + cl) * 64;
            bfx8 k0 = *reinterpret_cast<const bfx8*>(kr + sw0);
            bfx8 k1 = *reinterpret_cast<const bfx8*>(kr + (sw0 ^ 32));
            accS[nt] = mfma16(k0, aq0, accS[nt]);
            accS[nt] = mfma16(k1, aq1, accS[nt]);
        }
        __builtin_amdgcn_s_setprio(0);

        float s[4][4];
        float pm[4];
#pragma unroll
        for (int nt = 0; nt < 4; nt++) {
            s[nt][0] = fmaf(accS[nt][0], SC2, mk[nt].x);
            s[nt][1] = fmaf(accS[nt][1], SC2, mk[nt].y);
            s[nt][2] = fmaf(accS[nt][2], SC2, mk[nt].z);
            s[nt][3] = fmaf(accS[nt][3], SC2, mk[nt].w);
            pm[nt] = fmaxf(fmaxf(s[nt][0], s[nt][1]), fmaxf(s[nt][2], s[nt][3]));
        }
        float tmax = fmaxf(fmaxf(pm[0], pm[1]), fmaxf(pm[2], pm[3]));
        if (!__all(tmax - m0 <= 11.5f)) {
            tmax = fmaxf(tmax, __shfl_xor(tmax, 16, 64));
            tmax = fmaxf(tmax, __shfl_xor(tmax, 32, 64));
            float mn = fmaxf(m0, tmax);
            float al = __builtin_amdgcn_exp2f(m0 - mn);
            m0 = mn;
            l0 *= al;
#pragma unroll
            for (int dt = 0; dt < 4; dt++) accO[dt] *= al;
        }

        float rs = 0.f;
#pragma unroll
        for (int nt = 0; nt < 4; nt++) {
            float p0 = __builtin_amdgcn_exp2f(s[nt][0] - m0);
            float p1 = __builtin_amdgcn_exp2f(s[nt][1] - m0);
            float p2 = __builtin_amdgcn_exp2f(s[nt][2] - m0);
            float p3 = __builtin_amdgcn_exp2f(s[nt][3] - m0);
            rs += (p0 + p1) + (p2 + p3);
            uint2 u;
            u.x = pack2bf(p0, p1);
            u.y = pack2bf(p2, p3);
            *reinterpret_cast<uint2*>(psw + cl * 72 + nt * 16 + cg * 4) = u;
        }
        rs += __shfl_xor(rs, 16, 64);
        rs += __shfl_xor(rs, 32, 64);
        l0 += rs;

        bfx8 pf0 = *reinterpret_cast<const bfx8*>(psw + cl * 72 + cg * 8);
        bfx8 pf1 = *reinterpret_cast<const bfx8*>(psw + cl * 72 + 32 + cg * 8);
        __builtin_amdgcn_s_setprio(1);
#pragma unroll
        for (int dt = 0; dt < 4; dt++) {
            const unsigned short* vr = vsb + (dt * 16 + cl) * 64;
            bfx8 v0 = *reinterpret_cast<const bfx8*>(vr + sw0);
            bfx8 v1 = *reinterpret_cast<const bfx8*>(vr + (sw0 ^ 32));
            accO[dt] = mfma16(v0, pf0, accO[dt]);
            accO[dt] = mfma16(v1, pf1, accO[dt]);
        }
        __builtin_amdgcn_s_setprio(0);
        __syncthreads();
        cur ^= 1;
    }

    float rl = 1.0f / l0;
    unsigned short* aorow = ao + (size_t)(b * SEQ + qb + w * 16 + cl) * DIM + hd * DHD;
#pragma unroll
    for (int dt = 0; dt < 4; dt++) {
        uint2 u;
        u.x = pack2bf(accO[dt][0] * rl, accO[dt][1] * rl);
        u.y = pack2bf(accO[dt][2] * rl, accO[dt][3] * rl);
        *reinterpret_cast<uint2*>(aorow + dt * 16 + cg * 4) = u;
    }
}

// ---------------- fused LN2 + gating ----------------
__global__ __launch_bounds__(256) void gate_kernel(const float* __restrict__ x2,
                                                   const float* __restrict__ lng,
                                                   const float* __restrict__ lnb,
                                                   const float* __restrict__ Wg,
                                                   const float* __restrict__ bg,
                                                   unsigned short* __restrict__ xn2b,
                                                   int* __restrict__ idx,
                                                   float* __restrict__ wts,
                                                   float* __restrict__ me_part) {
    __shared__ float bme[8];
    if (threadIdx.x < 8) bme[threadIdx.x] = 0.f;
    __syncthreads();
    int w = threadIdx.x >> 6, lane = threadIdx.x & 63;
    int t = blockIdx.x * 4 + w;
    const float* xr = x2 + (size_t)t * DIM + lane * 16;
    float4 xv[4];
    float s = 0.f, s2 = 0.f;
#pragma unroll
    for (int q = 0; q < 4; q++) {
        xv[q] = *reinterpret_cast<const float4*>(xr + q * 4);
        s  += xv[q].x + xv[q].y + xv[q].z + xv[q].w;
        s2 += xv[q].x * xv[q].x + xv[q].y * xv[q].y + xv[q].z * xv[q].z + xv[q].w * xv[q].w;
    }
    for (int o = 32; o > 0; o >>= 1) {
        s  += __shfl_xor(s,  o, 64);
        s2 += __shfl_xor(s2, o, 64);
    }
    float mu = s * (1.0f / DIM);
    float rstd = rsqrtf(s2 * (1.0f / DIM) - mu * mu + 1e-5f);
    float acc[8];
#pragma unroll
    for (int e = 0; e < 8; e++) acc[e] = 0.f;
    unsigned short ob[16];
#pragma unroll
    for (int q = 0; q < 4; q++) {
        float4 gv = *reinterpret_cast<const float4*>(lng + lane * 16 + q * 4);
        float4 bv = *reinterpret_cast<const float4*>(lnb + lane * 16 + q * 4);
        float xn0 = (xv[q].x - mu) * rstd * gv.x + bv.x;
        float xn1 = (xv[q].y - mu) * rstd * gv.y + bv.y;
        float xn2 = (xv[q].z - mu) * rstd * gv.z + bv.z;
        float xn3 = (xv[q].w - mu) * rstd * gv.w + bv.w;
        ob[q * 4 + 0] = f2bf(xn0);
        ob[q * 4 + 1] = f2bf(xn1);
        ob[q * 4 + 2] = f2bf(xn2);
        ob[q * 4 + 3] = f2bf(xn3);
        const float* wr = Wg + (size_t)(lane * 16 + q * 4) * 8;
#pragma unroll
        for (int e = 0; e < 8; e++) acc[e] += xn0 * wr[e];
#pragma unroll
        for (int e = 0; e < 8; e++) acc[e] += xn1 * wr[8 + e];
#pragma unroll
        for (int e = 0; e < 8; e++) acc[e] += xn2 * wr[16 + e];
#pragma unroll
        for (int e = 0; e < 8; e++) acc[e] += xn3 * wr[24 + e];
    }
    unsigned short* op = xn2b + (size_t)t * DIM + lane * 16;
    *reinterpret_cast<shortx8*>(op)     = *reinterpret_cast<shortx8*>(&ob[0]);
    *reinterpret_cast<shortx8*>(op + 8) = *reinterpret_cast<shortx8*>(&ob[8]);
    for (int o = 32; o > 0; o >>= 1)
#pragma unroll
        for (int e = 0; e < 8; e++) acc[e] += __shfl_xor(acc[e], o, 64);
    if (lane == 0) {
        float p[8];
        float mx = -3e38f;
#pragma unroll
        for (int e = 0; e < 8; e++) { acc[e] += bg[e]; mx = fmaxf(mx, acc[e]); }
        float se = 0.f;
#pragma unroll
        for (int e = 0; e < 8; e++) { p[e] = expf(acc[e] - mx); se += p[e]; }
#pragma unroll
        for (int e = 0; e < 8; e++) p[e] /= se;
        int i0 = 0; float v0 = p[0];
#pragma unroll
        for (int e = 1; e < 8; e++) if (p[e] > v0) { v0 = p[e]; i0 = e; }
        int i1 = -1; float v1 = -3e38f;
#pragma unroll
        for (int e = 0; e < 8; e++) if (e != i0 && p[e] > v1) { v1 = p[e]; i1 = e; }
        float sw = v0 + v1;
        idx[t * 2]     = i0;
        idx[t * 2 + 1] = i1;
        wts[t * 2]     = v0 / sw;
        wts[t * 2 + 1] = v1 / sw;
#pragma unroll
        for (int e = 0; e < 8; e++) atomicAdd(&bme[e], p[e]);
    }
    __syncthreads();
    if (threadIdx.x < 8) me_part[(size_t)blockIdx.x * 8 + threadIdx.x] = bme[threadIdx.x];
}

// ---------------- routing pass 1 ----------------
__global__ __launch_bounds__(256) void route1_kernel(const int* __restrict__ idx,
                                                     int* __restrict__ cnt,
                                                     int* __restrict__ posl) {
    __shared__ int lh[8];
    __shared__ int gb[8];
    int tid = threadIdx.x;
    int t = blockIdx.x * 256 + tid;
    if (tid < 8) lh[tid] = 0;
    __syncthreads();
    int i0 = idx[t * 2], i1 = idx[t * 2 + 1];
    int r0 = atomicAdd(&lh[i0], 1);
    int r1 = atomicAdd(&lh[i1], 1);
    __syncthreads();
    if (tid < 8) gb[tid] = atomicAdd(&cnt[tid], lh[tid]);
    __syncthreads();
    posl[t * 2]     = gb[i0] + r0;
    posl[t * 2 + 1] = gb[i1] + r1;
}

__global__ void prefix_kernel(const int* __restrict__ cnt, int* __restrict__ goff) {
    if (threadIdx.x == 0) {
        int s = 0;
        for (int e = 0; e < 8; e++) { goff[e] = s; s += cnt[e]; }
        goff[8] = s;
    }
}

// ---------------- routing pass 2 ----------------
__global__ __launch_bounds__(256) void route2_kernel(const int* __restrict__ idx,
                                                     const int* __restrict__ goff,
                                                     const int* __restrict__ posl,
                                                     int* __restrict__ gtok,
                                                     int* __restrict__ tpos) {
    int t = blockIdx.x * 256 + threadIdx.x;
#pragma unroll
    for (int j = 0; j < 2; j++) {
        int e = idx[t * 2 + j];
        int p = goff[e] + posl[t * 2 + j];
        gtok[p] = t;
        tpos[t * 2 + j] = p;
    }
}

// ---------------- combine: eo is bf16 ----------------
__global__ __launch_bounds__(256) void combine_kernel(const float* __restrict__ x2,
                                                      const unsigned short* __restrict__ eo,
                                                      const float* __restrict__ wts,
                                                      const int* __restrict__ tpos,
                                                      float* __restrict__ out) {
    int t = blockIdx.x;
    int c = threadIdx.x * 4;
    float w0 = wts[t * 2], w1 = wts[t * 2 + 1];
    int p0 = tpos[t * 2], p1 = tpos[t * 2 + 1];
    float4 r = *reinterpret_cast<const float4*>(x2 + (size_t)t * DIM + c);
    ushort4 a4 = *reinterpret_cast<const ushort4*>(eo + (size_t)p0 * DIM + c);
    ushort4 b4 = *reinterpret_cast<const ushort4*>(eo + (size_t)p1 * DIM + c);
    float4 o;
    o.x = r.x + w0 * bf2f(a4.x) + w1 * bf2f(b4.x);
    o.y = r.y + w0 * bf2f(a4.y) + w1 * bf2f(b4.y);
    o.z = r.z + w0 * bf2f(a4.z) + w1 * bf2f(b4.z);
    o.w = r.w + w0 * bf2f(a4.w) + w1 * bf2f(b4.w);
    *reinterpret_cast<float4*>(out + (size_t)t * DIM + c) = o;
}

// ---------------- loss ----------------
__global__ __launch_bounds__(256) void loss_kernel(const float* __restrict__ me_part,
                                                   const int* __restrict__ cnt,
                                                   float* __restrict__ out) {
    __shared__ float red[256];
    int tid = threadIdx.x;
    int e = tid & 7, part = tid >> 3;
    float s = 0.f;
    for (int b = part; b < 1024; b += 32) s += me_part[(size_t)b * 8 + e];
    red[tid] = s;
    __syncthreads();
    if (tid < 64) {
        float v = red[tid] + red[tid + 64] + red[tid + 128] + red[tid + 192];
        red[tid] = v;
    }
    __syncthreads();
    if (tid < 8) {
        float v = red[tid] + red[tid + 8] + red[tid + 16] + red[tid + 24] +
                  red[tid + 32] + red[tid + 40] + red[tid + 48] + red[tid + 56];
        red[tid] = v;
    }
    __syncthreads();
    if (tid == 0) {
        float s2 = 0.f;
        for (int ee = 0; ee < 8; ee++)
            s2 += (red[ee] / 4096.0f) * ((float)cnt[ee] / 4096.0f);
        out[(size_t)TOK * DIM] = 8.0f * s2;
    }
}

extern "C" void kernel_launch(void* const* d_in, const int* in_sizes, int n_in,
                              void* d_out, int out_size, void* d_ws, size_t ws_size,
                              hipStream_t stream) {
    const float* x    = (const float*)d_in[0];
    const unsigned char* mask = (const unsigned char*)d_in[1];
    const float* ln1g = (const float*)d_in[2];
    const float* ln1b = (const float*)d_in[3];
    const float* Wqkv = (const float*)d_in[4];
    const float* bqkv = (const float*)d_in[5];
    const float* Wo   = (const float*)d_in[6];
    const float* bo   = (const float*)d_in[7];
    const float* ln2g = (const float*)d_in[8];
    const float* ln2b = (const float*)d_in[9];
    const float* Wg   = (const float*)d_in[10];
    const float* bg   = (const float*)d_in[11];
    const float* W1   = (const float*)d_in[12];
    const float* b1   = (const float*)d_in[13];
    const float* W2   = (const float*)d_in[14];
    const float* b2   = (const float*)d_in[15];
    float* out = (float*)d_out;

    char* ws = (char*)d_ws;
    int*   cnt  = (int*)(ws + 0);
    int*   goff = (int*)(ws + 128);
    size_t off = 1024;
    auto alloc = [&](size_t bytes) -> void* {
        void* p = ws + off;
        off += (bytes + 255) & ~(size_t)255;
        return p;
    };
    const size_t SZ_QKVB = (size_t)TOK * 3 * DIM * 2;
    const size_t SZ_HB   = (size_t)2 * TOK * HIDN * 2;
    char* R1 = (char*)alloc(SZ_HB > SZ_QKVB ? SZ_HB : SZ_QKVB);
    const size_t SZ_R2 = (size_t)2 * TOK * DIM * 2 + (size_t)3 * DIM * DIM * 2 +
                         (size_t)DIM * DIM * 2;
    char* R2 = (char*)alloc(SZ_R2);
    unsigned short* qkvb  = (unsigned short*)R1;
    unsigned short* hb    = (unsigned short*)R1;
    unsigned short* eo16  = (unsigned short*)R2;
    unsigned short* xn1   = (unsigned short*)R2;
    unsigned short* aob   = (unsigned short*)(R2 + (size_t)TOK * DIM * 2);
    unsigned short* wqkvb = (unsigned short*)(R2 + (size_t)2 * TOK * DIM * 2);
    unsigned short* wob   = (unsigned short*)(R2 + (size_t)2 * TOK * DIM * 2 +
                                              (size_t)3 * DIM * DIM * 2);
    float*          x2    = (float*)alloc((size_t)TOK * DIM * 4);
    unsigned short* xn2b  = (unsigned short*)alloc((size_t)TOK * DIM * 2);
    unsigned short* w1t   = (unsigned short*)alloc((size_t)NE * DIM * HIDN * 2);
    unsigned short* w2t   = (unsigned short*)alloc((size_t)NE * DIM * HIDN * 2);
    unsigned short* ktg   = (unsigned short*)alloc((size_t)BATCH * NH * SEQ * DHD * 2);
    unsigned short* vtg   = (unsigned short*)alloc((size_t)BATCH * NH * DHD * SEQ * 2);
    float*          maskf = (float*)alloc((size_t)BATCH * SEQ * 4);
    float*          mep   = (float*)alloc((size_t)1024 * 8 * 4);
    int*            idxp  = (int*)alloc((size_t)TOK * 2 * 4);
    float*          wtsp  = (float*)alloc((size_t)TOK * 2 * 4);
    int*            posl  = (int*)alloc((size_t)TOK * 2 * 4);
    int*            gtok  = (int*)alloc((size_t)2 * TOK * 4);
    int*            tpos  = (int*)alloc((size_t)TOK * 2 * 4);

    hipMemsetAsync(ws, 0, 256, stream);

    cvt_kernel<<<3 * DIM * DIM / 1024, 256, 0, stream>>>(Wqkv, wqkvb, 3 * DIM * DIM);
    cvt_kernel<<<DIM * DIM / 1024, 256, 0, stream>>>(Wo, wob, DIM * DIM);
    transpose_cvt_kernel<<<dim3(HIDN / 64, DIM / 64, NE), 256, 0, stream>>>(W1, w1t, DIM, HIDN);
    transpose_cvt_kernel<<<dim3(DIM / 64, HIDN / 64, NE), 256, 0, stream>>>(W2, w2t, HIDN, DIM);

    ln_kernel<<<TOK, 256, 0, stream>>>(x, ln1g, ln1b, xn1);

    gemm_kernel<0, false><<<dim3(24, 32, 1), 256, 0, stream>>>(
        xn1, wqkvb, qkvb, bqkv, nullptr, nullptr, nullptr, nullptr, TOK, 3 * DIM, DIM);

    kvprep_kernel<<<dim3(SEQ / 64, NH, BATCH), 256, 0, stream>>>(qkvb, ktg, vtg, mask, maskf);

    attn_kernel<<<dim3(SEQ / 128, NH, BATCH), 512, 0, stream>>>(qkvb, ktg, vtg, maskf, aob);

    gemm_kernel<1, false><<<dim3(8, 32, 1), 256, 0, stream>>>(
        aob, wob, x2, bo, x, nullptr, nullptr, nullptr, TOK, DIM, DIM);

    gate_kernel<<<TOK / 4, 256, 0, stream>>>(x2, ln2g, ln2b, Wg, bg, xn2b,
                                             idxp, wtsp, mep);
    route1_kernel<<<TOK / 256, 256, 0, stream>>>(idxp, cnt, posl);
    prefix_kernel<<<1, 64, 0, stream>>>(cnt, goff);
    route2_kernel<<<TOK / 256, 256, 0, stream>>>(idxp, goff, posl, gtok, tpos);

    gemm_kernel<2, true><<<dim3(16, 32, 8), 256, 0, stream>>>(
        xn2b, w1t, hb, b1, nullptr, cnt, goff, gtok, TOK, HIDN, DIM);

    gemm_kernel<3, false><<<dim3(8, 32, 8), 256, 0, stream>>>(
        hb, w2t, eo16, b2, nullptr, cnt, goff, nullptr, TOK, DIM, HIDN);

    combine_kernel<<<TOK, 256, 0, stream>>>(x2, eo16, wtsp, tpos, out);
    loss_kernel<<<1, 256, 0, stream>>>(mep, cnt, out);
}